// Round 4
// baseline (352.157 us; speedup 1.0000x reference)
//
#include <hip/hip_runtime.h>
#include <hip/hip_bf16.h>

// ReLU-LSTM fused, round 4: precast f32->bf16 (pre-swizzled) into d_ws, then
// 8-phase counted-vmcnt 256-row GEMM using 32x32x16 MFMA + XCD swizzle,
// 4-gate shared-A accumulation, in-register LSTM epilogue.

#define HID 2048
#define BATCH_N 4096
#define KTOT 4096
#define BK 64

typedef __attribute__((ext_vector_type(4))) float f32x4;
typedef __attribute__((ext_vector_type(16))) float f32x16;
typedef __attribute__((ext_vector_type(8))) short bf16x8;

__device__ __forceinline__ short f2bf(float f) {
    union { float f; unsigned u; } v; v.f = f;
    unsigned r = v.u + 0x7FFFu + ((v.u >> 16) & 1u);
    return (short)(r >> 16);
}

__device__ __forceinline__ float fast_tanh(float v) {
    float e = __expf(2.0f * v);
    return 1.0f - 2.0f / (e + 1.0f);
}

__device__ __forceinline__ void gload_lds16(const short* g, short* l) {
    __builtin_amdgcn_global_load_lds(
        (const __attribute__((address_space(1))) unsigned int*)g,
        (__attribute__((address_space(3))) unsigned int*)l, 16, 0, 0);
}

// ---------------------------------------------------------------------------
// Kernel 1: precast f32 -> bf16 with within-64 K-swizzle keyed on (row&7).
// Stored col = (k & ~63) | ((k&63) ^ ((row&7)<<3)) so a LINEAR global_load_lds
// stage yields a swizzled LDS tile (rule 21).
// ---------------------------------------------------------------------------
struct CastParams {
    const float* x; const float* h;
    const float* Wx[4]; const float* Wh[4];
    short* A; short* B;
};

__global__ __launch_bounds__(256) void precast_kernel(CastParams q) {
    const long A_CH = (long)BATCH_N * (KTOT / 8);   // 2^21 16B-chunks
    const long B_CH = 4L * HID * (KTOT / 8);        // 2^22
    const long total = A_CH + B_CH;
    for (long idx = (long)blockIdx.x * 256 + threadIdx.x; idx < total;
         idx += (long)gridDim.x * 256) {
        const float* src; short* dst; int row, k;
        if (idx < A_CH) {
            row = (int)(idx >> 9);
            k = (int)(idx & 511) << 3;
            src = (k < HID) ? &q.x[(size_t)row * HID + k]
                            : &q.h[(size_t)row * HID + (k - HID)];
            dst = &q.A[(size_t)row * KTOT];
        } else {
            long r = idx - A_CH;
            int g = (int)(r >> 20);
            int rem = (int)(r & ((1 << 20) - 1));
            row = rem >> 9;
            k = (rem & 511) << 3;
            src = (k < HID) ? &q.Wx[g][(size_t)row * HID + k]
                            : &q.Wh[g][(size_t)row * HID + (k - HID)];
            dst = &q.B[((size_t)g * HID + row) * KTOT];
        }
        float4 v0 = *(const float4*)src;
        float4 v1 = *(const float4*)(src + 4);
        int col = (k & ~63) | ((k & 63) ^ ((row & 7) << 3));
        bf16x8 s;
        s[0] = f2bf(v0.x); s[1] = f2bf(v0.y); s[2] = f2bf(v0.z); s[3] = f2bf(v0.w);
        s[4] = f2bf(v1.x); s[5] = f2bf(v1.y); s[6] = f2bf(v1.z); s[7] = f2bf(v1.w);
        *(bf16x8*)&dst[col] = s;
    }
}

// ---------------------------------------------------------------------------
// Kernel 2: 8-phase GEMM+LSTM, 32x32x16 MFMA. Block = 256 rows x 64 cols x 4
// gates, 512 threads = 8 waves (4M x 2N), per-wave 64x32 per gate.
// Stage schedule identical to round 3 (validated region-disjoint).
// ---------------------------------------------------------------------------
struct GemmParams {
    const short* A; const short* B;
    const float* bx[4];
    const float* c;
    float* oh; float* oc;
};

__global__ __launch_bounds__(512, 2) void gemm_lstm_8ph(GemmParams p) {
    __shared__ short sA[2][16384];   // [buf][4 units x 4096]  (256 rows x 64)
    __shared__ short sB[2][16384];   // [buf][4 gates x 4096]  (64 rows x 64)

    const int t = threadIdx.x;
    const int wave = t >> 6;
    const int lane = t & 63;
    const int wr = wave >> 1;            // rows wr*64
    const int wc = wave & 1;             // cols wc*32
    const int l31 = lane & 31;
    const int kb_ = (lane >> 5) * 8;     // k sub-offset within frag
    const int sw = (l31 & 7) << 3;       // swizzle key (row&7)<<3

    // 4 k-slot offsets (elements), shared by A and B reads (row&7 identical)
    int kx[4];
    #pragma unroll
    for (int ks = 0; ks < 4; ++ks) kx[ks] = (ks * 16 + kb_) ^ sw;

    // XCD-aware bijective swizzle of the flat block index (512 = 8*64)
    const int b0 = blockIdx.x;
    const int nb = ((b0 & 7) << 6) | (b0 >> 3);
    const int bm = (nb & 15) * 256;
    const int bn = (nb >> 4) * 64;

    const int aOff = (wr * 64 + l31) * 64;   // + m*2048 elems (32 rows)
    const int bOff = (wc * 32 + l31) * 64;   // + g*4096

    const short* aSrc = p.A + (size_t)(bm + (t >> 3)) * KTOT + (t & 7) * 8;
    const short* bSrc = p.B + (size_t)(bn + (t >> 3)) * KTOT + (t & 7) * 8;
    const int ldsT = t * 8;                  // linear dest: t*16B

    f32x16 acc[4][2];                        // [gate][m-frag]
    #pragma unroll
    for (int g = 0; g < 4; ++g)
        #pragma unroll
        for (int m = 0; m < 2; ++m)
            #pragma unroll
            for (int r = 0; r < 16; ++r)
                acc[g][m][r] = 0.f;

    bf16x8 a[2][4];                          // [m-frag][k-slot]
    bf16x8 b[4];                             // [k-slot]

#define STAGE_A(bf, u, kp) gload_lds16(aSrc + (size_t)(u) * 64 * KTOT + (kp), \
                                       &sA[bf][(u) * 4096 + ldsT])
#define STAGE_B(bf, g, kp) gload_lds16(bSrc + (size_t)(g) * HID * KTOT + (kp), \
                                       &sB[bf][(g) * 4096 + ldsT])
#define READ_A(bf) do { _Pragma("unroll") for (int m = 0; m < 2; ++m) \
        _Pragma("unroll") for (int ks = 0; ks < 4; ++ks) \
            a[m][ks] = *(const bf16x8*)&sA[bf][aOff + m * 2048 + kx[ks]]; } while (0)
#define READ_B(bf, g) do { _Pragma("unroll") for (int ks = 0; ks < 4; ++ks) \
            b[ks] = *(const bf16x8*)&sB[bf][(g) * 4096 + bOff + kx[ks]]; } while (0)
#define MFMA_G(g) do { __builtin_amdgcn_s_setprio(1); \
        _Pragma("unroll") for (int ks = 0; ks < 4; ++ks) \
        _Pragma("unroll") for (int m = 0; m < 2; ++m) \
            acc[g][m] = __builtin_amdgcn_mfma_f32_32x32x16_bf16( \
                a[m][ks], b[ks], acc[g][m], 0, 0, 0); \
        __builtin_amdgcn_s_setprio(0); } while (0)
#define BAR() __builtin_amdgcn_s_barrier()
#define VMCNT6() asm volatile("s_waitcnt vmcnt(6)" ::: "memory")
#define LGKM8() asm volatile("s_waitcnt lgkmcnt(8)" ::: "memory")

    // ---- prologue: tile0 -> dbuf0 (8 units), tile1 -> dbuf1 (A + Bg0,Bg1) ----
    STAGE_A(0, 0, 0); STAGE_A(0, 1, 0); STAGE_A(0, 2, 0); STAGE_A(0, 3, 0);
    STAGE_B(0, 0, 0); STAGE_B(0, 1, 0); STAGE_B(0, 2, 0); STAGE_B(0, 3, 0);
    STAGE_A(1, 0, BK); STAGE_A(1, 1, BK); STAGE_A(1, 2, BK); STAGE_A(1, 3, BK);
    STAGE_B(1, 0, BK); STAGE_B(1, 1, BK);
    VMCNT6();
    BAR();

    for (int it = 0; it < KTOT / (2 * BK); ++it) {
        const int kc1 = ((2 * it + 1) * BK) & (KTOT - 1);
        const int kc2 = ((2 * it + 2) * BK) & (KTOT - 1);
        const int kc3 = ((2 * it + 3) * BK) & (KTOT - 1);

        // P1
        READ_A(0); READ_B(0, 0);
        STAGE_B(1, 2, kc1); STAGE_B(1, 3, kc1);
        LGKM8();
        BAR(); MFMA_G(0); BAR();
        // P2
        READ_B(0, 1);
        STAGE_A(0, 0, kc2); STAGE_A(0, 1, kc2);
        BAR(); MFMA_G(1); BAR();
        // P3
        READ_B(0, 2);
        STAGE_A(0, 2, kc2); STAGE_A(0, 3, kc2);
        BAR(); MFMA_G(2); BAR();
        // P4
        READ_B(0, 3);
        STAGE_B(0, 0, kc2); STAGE_B(0, 1, kc2);
        VMCNT6();
        BAR(); MFMA_G(3); BAR();
        // P5
        READ_A(1); READ_B(1, 0);
        STAGE_B(0, 2, kc2); STAGE_B(0, 3, kc2);
        LGKM8();
        BAR(); MFMA_G(0); BAR();
        // P6
        READ_B(1, 1);
        STAGE_A(1, 0, kc3); STAGE_A(1, 1, kc3);
        BAR(); MFMA_G(1); BAR();
        // P7
        READ_B(1, 2);
        STAGE_A(1, 2, kc3); STAGE_A(1, 3, kc3);
        BAR(); MFMA_G(2); BAR();
        // P8
        READ_B(1, 3);
        STAGE_B(1, 0, kc3); STAGE_B(1, 1, kc3);
        VMCNT6();
        BAR(); MFMA_G(3); BAR();
    }
    asm volatile("s_waitcnt vmcnt(0)" ::: "memory");  // drain before exit

    // ---- epilogue: bias + ReLU/tanh + cell update ----
    // 32x32 C/D layout: col = lane&31, row = (reg&3) + 8*(reg>>2) + 4*(lane>>5)
    const int col = bn + wc * 32 + l31;
    float bias[4];
    #pragma unroll
    for (int g = 0; g < 4; ++g) bias[g] = p.bx[g][col];

    #pragma unroll
    for (int m = 0; m < 2; ++m) {
        #pragma unroll
        for (int r = 0; r < 16; ++r) {
            int row = bm + wr * 64 + m * 32 + (r & 3) + 8 * (r >> 2) + 4 * (lane >> 5);
            float pf = acc[0][m][r] + bias[0];
            float pi = acc[1][m][r] + bias[1];
            float pc = acc[2][m][r] + bias[2];
            float po = acc[3][m][r] + bias[3];
            float fg = fmaxf(pf, 0.f);
            float ig = fmaxf(pi, 0.f);
            float og = fmaxf(po, 0.f);
            float ct = fast_tanh(pc);
            float cv = p.c[(size_t)row * HID + col];
            float cn = fg * cv + ig * ct;
            float hn = og * fast_tanh(cn);
            p.oh[(size_t)row * HID + col] = hn;
            p.oc[(size_t)row * HID + col] = cn;
        }
    }
#undef STAGE_A
#undef STAGE_B
#undef READ_A
#undef READ_B
#undef MFMA_G
#undef BAR
#undef VMCNT6
#undef LGKM8
}

// ---------------------------------------------------------------------------
// Fallback (round-1 fused kernel) if d_ws is too small.
// ---------------------------------------------------------------------------
struct Params {
    const float* x; const float* h; const float* c;
    const float* Wx[4]; const float* Wh[4]; const float* bx[4];
    float* oh; float* oc;
};

__global__ __launch_bounds__(256, 2) void relulstm_fallback(Params p) {
    __shared__ short sA[128 * 64];
    __shared__ short sB[4][64 * 64];
    const int t = threadIdx.x;
    const int bm = blockIdx.x * 128;
    const int bn = blockIdx.y * 64;
    const int wave = t >> 6;
    const int lane = t & 63;
    const int wm = (wave >> 1) * 64;
    const int wn = (wave & 1) * 32;
    const int lr = lane & 15;
    const int lk = (lane >> 4) * 8;

    f32x4 acc[4][4][2];
    #pragma unroll
    for (int g = 0; g < 4; ++g)
        #pragma unroll
        for (int m = 0; m < 4; ++m)
            #pragma unroll
            for (int n = 0; n < 2; ++n)
                acc[g][m][n] = (f32x4){0.f, 0.f, 0.f, 0.f};

    for (int k0 = 0; k0 < 2 * HID; k0 += BK) {
        const bool xpart = (k0 < HID);
        const int kb = k0 & (HID - 1);
        const float* __restrict__ srcA = xpart ? p.x : p.h;
        #pragma unroll
        for (int i2 = 0; i2 < 8; ++i2) {
            int cidx = t + i2 * 256;
            int row = cidx >> 4;
            int kc = cidx & 15;
            float4 v = *(const float4*)&srcA[(size_t)(bm + row) * HID + kb + kc * 4];
            int idx = row * BK + ((kc * 4) ^ ((row & 7) << 3));
            short4 s;
            s.x = f2bf(v.x); s.y = f2bf(v.y); s.z = f2bf(v.z); s.w = f2bf(v.w);
            *(short4*)&sA[idx] = s;
        }
        #pragma unroll
        for (int i2 = 0; i2 < 16; ++i2) {
            const int g = i2 >> 2;
            int rem = t + (i2 & 3) * 256;
            int row = rem >> 4;
            int kc = rem & 15;
            const float* __restrict__ srcB = xpart ? p.Wx[g] : p.Wh[g];
            float4 v = *(const float4*)&srcB[(size_t)(bn + row) * HID + kb + kc * 4];
            int idx = row * BK + ((kc * 4) ^ ((row & 7) << 3));
            short4 s;
            s.x = f2bf(v.x); s.y = f2bf(v.y); s.z = f2bf(v.z); s.w = f2bf(v.w);
            *(short4*)&sB[g][idx] = s;
        }
        __syncthreads();
        #pragma unroll
        for (int kk = 0; kk < 2; ++kk) {
            bf16x8 a[4];
            #pragma unroll
            for (int m = 0; m < 4; ++m) {
                int row = wm + m * 16 + lr;
                int kidx = (kk * 32 + lk) ^ ((row & 7) << 3);
                a[m] = *(const bf16x8*)&sA[row * BK + kidx];
            }
            #pragma unroll
            for (int g = 0; g < 4; ++g) {
                #pragma unroll
                for (int n = 0; n < 2; ++n) {
                    int brow = wn + n * 16 + lr;
                    int kidx = (kk * 32 + lk) ^ ((brow & 7) << 3);
                    bf16x8 b = *(const bf16x8*)&sB[g][brow * BK + kidx];
                    #pragma unroll
                    for (int m = 0; m < 4; ++m)
                        acc[g][m][n] = __builtin_amdgcn_mfma_f32_16x16x32_bf16(
                            a[m], b, acc[g][m][n], 0, 0, 0);
                }
            }
        }
        __syncthreads();
    }

    float bias[4][2];
    #pragma unroll
    for (int g = 0; g < 4; ++g)
        #pragma unroll
        for (int n = 0; n < 2; ++n)
            bias[g][n] = p.bx[g][bn + wn + n * 16 + lr];

    #pragma unroll
    for (int m = 0; m < 4; ++m) {
        int rbase = bm + wm + m * 16 + (lane >> 4) * 4;
        #pragma unroll
        for (int r = 0; r < 4; ++r) {
            int row = rbase + r;
            #pragma unroll
            for (int n = 0; n < 2; ++n) {
                int col = bn + wn + n * 16 + lr;
                float pf = acc[0][m][n][r] + bias[0][n];
                float pi = acc[1][m][n][r] + bias[1][n];
                float pc = acc[2][m][n][r] + bias[2][n];
                float po = acc[3][m][n][r] + bias[3][n];
                float fg = fmaxf(pf, 0.f);
                float ig = fmaxf(pi, 0.f);
                float og = fmaxf(po, 0.f);
                float ct = fast_tanh(pc);
                float cv = p.c[(size_t)row * HID + col];
                float cn = fg * cv + ig * ct;
                float hn = og * fast_tanh(cn);
                p.oh[(size_t)row * HID + col] = hn;
                p.oc[(size_t)row * HID + col] = cn;
            }
        }
    }
}

extern "C" void kernel_launch(void* const* d_in, const int* in_sizes, int n_in,
                              void* d_out, int out_size, void* d_ws, size_t ws_size,
                              hipStream_t stream) {
    (void)in_sizes; (void)n_in; (void)out_size;
    const size_t A_BYTES = (size_t)BATCH_N * KTOT * 2;
    const size_t B_BYTES = (size_t)4 * HID * KTOT * 2;

    if (ws_size >= A_BYTES + B_BYTES) {
        short* A = (short*)d_ws;
        short* B = A + (size_t)BATCH_N * KTOT;

        CastParams q;
        q.x = (const float*)d_in[0];
        q.h = (const float*)d_in[1];
        for (int g = 0; g < 4; ++g) {
            q.Wx[g] = (const float*)d_in[3 + 3 * g];
            q.Wh[g] = (const float*)d_in[5 + 3 * g];
        }
        q.A = A; q.B = B;
        precast_kernel<<<2048, 256, 0, stream>>>(q);

        GemmParams p;
        p.A = A; p.B = B;
        p.c = (const float*)d_in[2];
        for (int g = 0; g < 4; ++g) p.bx[g] = (const float*)d_in[4 + 3 * g];
        p.oh = (float*)d_out;
        p.oc = (float*)d_out + (size_t)BATCH_N * HID;
        gemm_lstm_8ph<<<dim3(512), 512, 0, stream>>>(p);
    } else {
        Params p;
        p.x = (const float*)d_in[0];
        p.h = (const float*)d_in[1];
        p.c = (const float*)d_in[2];
        for (int g = 0; g < 4; ++g) {
            p.Wx[g] = (const float*)d_in[3 + 3 * g];
            p.bx[g] = (const float*)d_in[4 + 3 * g];
            p.Wh[g] = (const float*)d_in[5 + 3 * g];
        }
        p.oh = (float*)d_out;
        p.oc = (float*)d_out + (size_t)BATCH_N * HID;
        dim3 grid(BATCH_N / 128, HID / 64);
        relulstm_fallback<<<grid, 256, 0, stream>>>(p);
    }
}

// Round 5
// 331.257 us; speedup vs baseline: 1.0631x; 1.0631x over previous
//
#include <hip/hip_runtime.h>
#include <hip/hip_bf16.h>

// ReLU-LSTM fused, round 5: precast f32->bf16 (pre-swizzled) into d_ws, then
// 8-window register-read-ahead GEMM (reads one window early into ping-pong
// register sets; 1 barrier/window; counted vmcnt(4) guards), 16x16x32 MFMA,
// 4-gate shared-A accumulation, in-register LSTM epilogue.

#define HID 2048
#define BATCH_N 4096
#define KTOT 4096
#define BK 64

typedef __attribute__((ext_vector_type(4))) float f32x4;
typedef __attribute__((ext_vector_type(8))) short bf16x8;

__device__ __forceinline__ short f2bf(float f) {
    union { float f; unsigned u; } v; v.f = f;
    unsigned r = v.u + 0x7FFFu + ((v.u >> 16) & 1u);
    return (short)(r >> 16);
}

__device__ __forceinline__ float fast_tanh(float v) {
    float e = __expf(2.0f * v);
    return 1.0f - 2.0f / (e + 1.0f);
}

__device__ __forceinline__ void gload_lds16(const short* g, short* l) {
    __builtin_amdgcn_global_load_lds(
        (const __attribute__((address_space(1))) unsigned int*)g,
        (__attribute__((address_space(3))) unsigned int*)l, 16, 0, 0);
}

// ---------------------------------------------------------------------------
// Kernel 1: precast f32 -> bf16 with within-64 K-swizzle keyed on (row&7).
// Stored col = (k & ~63) | ((k&63) ^ ((row&7)<<3)) so a LINEAR global_load_lds
// stage yields a swizzled LDS tile (rule 21).
// ---------------------------------------------------------------------------
struct CastParams {
    const float* x; const float* h;
    const float* Wx[4]; const float* Wh[4];
    short* A; short* B;
};

__global__ __launch_bounds__(256) void precast_kernel(CastParams q) {
    const long A_CH = (long)BATCH_N * (KTOT / 8);   // 2^21 16B-chunks
    const long B_CH = 4L * HID * (KTOT / 8);        // 2^22
    const long total = A_CH + B_CH;
    for (long idx = (long)blockIdx.x * 256 + threadIdx.x; idx < total;
         idx += (long)gridDim.x * 256) {
        const float* src; short* dst; int row, k;
        if (idx < A_CH) {
            row = (int)(idx >> 9);
            k = (int)(idx & 511) << 3;
            src = (k < HID) ? &q.x[(size_t)row * HID + k]
                            : &q.h[(size_t)row * HID + (k - HID)];
            dst = &q.A[(size_t)row * KTOT];
        } else {
            long r = idx - A_CH;
            int g = (int)(r >> 20);
            int rem = (int)(r & ((1 << 20) - 1));
            row = rem >> 9;
            k = (rem & 511) << 3;
            src = (k < HID) ? &q.Wx[g][(size_t)row * HID + k]
                            : &q.Wh[g][(size_t)row * HID + (k - HID)];
            dst = &q.B[((size_t)g * HID + row) * KTOT];
        }
        float4 v0 = *(const float4*)src;
        float4 v1 = *(const float4*)(src + 4);
        int col = (k & ~63) | ((k & 63) ^ ((row & 7) << 3));
        bf16x8 s;
        s[0] = f2bf(v0.x); s[1] = f2bf(v0.y); s[2] = f2bf(v0.z); s[3] = f2bf(v0.w);
        s[4] = f2bf(v1.x); s[5] = f2bf(v1.y); s[6] = f2bf(v1.z); s[7] = f2bf(v1.w);
        *(bf16x8*)&dst[col] = s;
    }
}

// ---------------------------------------------------------------------------
// Kernel 2: read-ahead pipelined GEMM+LSTM.
// Block = 256 rows x 64 cols x 4 gates, 512 threads = 8 waves (4M x 2N).
// Stage schedule (identical regions/windows to validated round 3):
//   P1: st d1.Bg2,Bg3@kc1 | rd b(d0,g1)      | MFMA g0(d0)
//   P2: st d0.A0,A1@kc2   | rd b(d0,g2)      | MFMA g1(d0)
//   P3: st d0.A2,A3@kc2   | rd b(d0,g3)      | MFMA g2(d0)
//   P4: VMCNT(4) | st d0.Bg0,Bg1@kc2 | rd A(d1)+b(d1,g0) | MFMA g3(d0)
//   P5: st d0.Bg2,Bg3@kc2 | rd b(d1,g1)      | MFMA g0(d1)
//   P6: st d1.A0,A1@kc3   | rd b(d1,g2)      | MFMA g1(d1)
//   P7: st d1.A2,A3@kc3   | rd b(d1,g3)      | MFMA g2(d1)
//   P8: VMCNT(4) | st d1.Bg0,Bg1@kc3 | rd A(d0)'+b(d0,g0)' | MFMA g3(d1)
// Reads in window w are consumed by MFMA in w+1 (ping-pong regs); one
// s_barrier + sched_barrier(0) per window. Guards: vmcnt(4) at start of
// P4/P8 (outstanding = the 4 loads of the 2 preceding windows).
// ---------------------------------------------------------------------------
struct GemmParams {
    const short* A; const short* B;
    const float* bx[4];
    const float* c;
    float* oh; float* oc;
};

__global__ __launch_bounds__(512, 2) void gemm_lstm_pipe(GemmParams p) {
    __shared__ short sA[2][16384];   // [buf][4 units x 4096]  (256 rows x 64)
    __shared__ short sB[2][16384];   // [buf][4 gates x 4096]  (64 rows x 64)

    const int t = threadIdx.x;
    const int wave = t >> 6;
    const int lane = t & 63;
    const int wr = wave >> 1;            // rows wr*64
    const int wc = wave & 1;             // cols wc*32
    const int lr = lane & 15;
    const int lk = (lane >> 4) * 8;
    const int sw = (lane & 7) << 3;      // (row&7)<<3 == (lr&7)<<3
    const int koff0 = lk ^ sw;
    const int koff1 = (32 + lk) ^ sw;

    const int bm = blockIdx.x * 256;
    const int bn = blockIdx.y * 64;

    const int aOff = (wr * 64 + lr) * 64;    // + m*1024 + koff
    const int bOff = (wc * 32 + lr) * 64;    // + g*4096 + n*1024 + koff

    const short* aSrc = p.A + (size_t)(bm + (t >> 3)) * KTOT + (t & 7) * 8;
    const short* bSrc = p.B + (size_t)(bn + (t >> 3)) * KTOT + (t & 7) * 8;
    const int ldsT = t * 8;                  // linear dest: t*16B

    f32x4 acc[4][4][2];
    #pragma unroll
    for (int g = 0; g < 4; ++g)
        #pragma unroll
        for (int m = 0; m < 4; ++m)
            #pragma unroll
            for (int n = 0; n < 2; ++n)
                acc[g][m][n] = (f32x4){0.f, 0.f, 0.f, 0.f};

    // ping-pong register sets (all statically indexed)
    bf16x8 aX[4][2], aY[4][2];
    bf16x8 bX[2][2], bY[2][2];

#define STAGE_A(bf, u, kp) gload_lds16(aSrc + (size_t)(u) * 64 * KTOT + (kp), \
                                       &sA[bf][(u) * 4096 + ldsT])
#define STAGE_B(bf, g, kp) gload_lds16(bSrc + (size_t)(g) * HID * KTOT + (kp), \
                                       &sB[bf][(g) * 4096 + ldsT])
#define READ_A_TO(dst, bf) do { _Pragma("unroll") for (int m = 0; m < 4; ++m) { \
        dst[m][0] = *(const bf16x8*)&sA[bf][aOff + m * 1024 + koff0]; \
        dst[m][1] = *(const bf16x8*)&sA[bf][aOff + m * 1024 + koff1]; } } while (0)
#define READ_B_TO(dst, bf, g) do { _Pragma("unroll") for (int n = 0; n < 2; ++n) { \
        dst[n][0] = *(const bf16x8*)&sB[bf][(g) * 4096 + bOff + n * 1024 + koff0]; \
        dst[n][1] = *(const bf16x8*)&sB[bf][(g) * 4096 + bOff + n * 1024 + koff1]; } } while (0)
#define MFMA_G(g, aS, bS) do { __builtin_amdgcn_s_setprio(1); \
        _Pragma("unroll") for (int kk = 0; kk < 2; ++kk) \
        _Pragma("unroll") for (int n = 0; n < 2; ++n) \
        _Pragma("unroll") for (int m = 0; m < 4; ++m) \
            acc[g][m][n] = __builtin_amdgcn_mfma_f32_16x16x32_bf16( \
                aS[m][kk], bS[n][kk], acc[g][m][n], 0, 0, 0); \
        __builtin_amdgcn_s_setprio(0); } while (0)
#define ENDW() do { __builtin_amdgcn_s_barrier(); \
                    __builtin_amdgcn_sched_barrier(0); } while (0)
#define VMCNT(n) asm volatile("s_waitcnt vmcnt(" #n ")" ::: "memory")

    // ---- prologue: tile0 -> d0 (8 units), tile1 -> d1 (A x4 + Bg0,Bg1) ----
    STAGE_A(0, 0, 0); STAGE_A(0, 1, 0); STAGE_A(0, 2, 0); STAGE_A(0, 3, 0);
    STAGE_B(0, 0, 0); STAGE_B(0, 1, 0); STAGE_B(0, 2, 0); STAGE_B(0, 3, 0);
    STAGE_A(1, 0, BK); STAGE_A(1, 1, BK); STAGE_A(1, 2, BK); STAGE_A(1, 3, BK);
    STAGE_B(1, 0, BK); STAGE_B(1, 1, BK);
    VMCNT(6);                    // tile0 (oldest 8) landed
    __builtin_amdgcn_s_barrier();
    READ_A_TO(aX, 0);            // pre-read for P1
    READ_B_TO(bX, 0, 0);
    ENDW();

    for (int it = 0; it < KTOT / (2 * BK); ++it) {
        const int kc1 = ((2 * it + 1) * BK) & (KTOT - 1);
        const int kc2 = ((2 * it + 2) * BK) & (KTOT - 1);  // wraps last iter (safe)
        const int kc3 = ((2 * it + 3) * BK) & (KTOT - 1);

        // P1: uses aX,bX ; reads bY <- b(d0,g1)
        READ_B_TO(bY, 0, 1);
        STAGE_B(1, 2, kc1); STAGE_B(1, 3, kc1);
        MFMA_G(0, aX, bX);
        ENDW();
        // P2: uses aX,bY ; reads bX <- b(d0,g2)
        READ_B_TO(bX, 0, 2);
        STAGE_A(0, 0, kc2); STAGE_A(0, 1, kc2);
        MFMA_G(1, aX, bY);
        ENDW();
        // P3: uses aX,bX ; reads bY <- b(d0,g3)
        READ_B_TO(bY, 0, 3);
        STAGE_A(0, 2, kc2); STAGE_A(0, 3, kc2);
        MFMA_G(2, aX, bX);
        ENDW();
        // P4: guard d1 ; uses aX,bY ; reads aY <- A(d1), bX <- b(d1,g0)
        VMCNT(4);
        READ_A_TO(aY, 1);
        READ_B_TO(bX, 1, 0);
        STAGE_B(0, 0, kc2); STAGE_B(0, 1, kc2);
        MFMA_G(3, aX, bY);
        ENDW();
        // P5: uses aY,bX ; reads bY <- b(d1,g1)
        READ_B_TO(bY, 1, 1);
        STAGE_B(0, 2, kc2); STAGE_B(0, 3, kc2);
        MFMA_G(0, aY, bX);
        ENDW();
        // P6: uses aY,bY ; reads bX <- b(d1,g2)
        READ_B_TO(bX, 1, 2);
        STAGE_A(1, 0, kc3); STAGE_A(1, 1, kc3);
        MFMA_G(1, aY, bY);
        ENDW();
        // P7: uses aY,bX ; reads bY <- b(d1,g3)
        READ_B_TO(bY, 1, 3);
        STAGE_A(1, 2, kc3); STAGE_A(1, 3, kc3);
        MFMA_G(2, aY, bX);
        ENDW();
        // P8: guard d0' ; uses aY,bY ; reads aX <- A(d0)', bX <- b(d0,g0)'
        VMCNT(4);
        READ_A_TO(aX, 0);
        READ_B_TO(bX, 0, 0);
        STAGE_B(1, 0, kc3); STAGE_B(1, 1, kc3);
        MFMA_G(3, aY, bY);
        ENDW();
    }
    asm volatile("s_waitcnt vmcnt(0)" ::: "memory");  // drain before exit

    // ---- epilogue: bias + ReLU/tanh + cell update ----
    // C/D layout (16x16): col = lane&15, row = (lane>>4)*4 + reg
    float bias[4][2];
    #pragma unroll
    for (int g = 0; g < 4; ++g)
        #pragma unroll
        for (int n = 0; n < 2; ++n)
            bias[g][n] = p.bx[g][bn + wc * 32 + n * 16 + lr];

    #pragma unroll
    for (int m = 0; m < 4; ++m) {
        int rbase = bm + wr * 64 + m * 16 + (lane >> 4) * 4;
        #pragma unroll
        for (int r = 0; r < 4; ++r) {
            int row = rbase + r;
            #pragma unroll
            for (int n = 0; n < 2; ++n) {
                int col = bn + wc * 32 + n * 16 + lr;
                float pf = acc[0][m][n][r] + bias[0][n];
                float pi = acc[1][m][n][r] + bias[1][n];
                float pc = acc[2][m][n][r] + bias[2][n];
                float po = acc[3][m][n][r] + bias[3][n];
                float fg = fmaxf(pf, 0.f);
                float ig = fmaxf(pi, 0.f);
                float og = fmaxf(po, 0.f);
                float ct = fast_tanh(pc);
                float cv = p.c[(size_t)row * HID + col];
                float cn = fg * cv + ig * ct;
                float hn = og * fast_tanh(cn);
                p.oh[(size_t)row * HID + col] = hn;
                p.oc[(size_t)row * HID + col] = cn;
            }
        }
    }
#undef STAGE_A
#undef STAGE_B
#undef READ_A_TO
#undef READ_B_TO
#undef MFMA_G
#undef ENDW
#undef VMCNT
}

// ---------------------------------------------------------------------------
// Fallback (round-1 fused kernel) if d_ws is too small.
// ---------------------------------------------------------------------------
struct Params {
    const float* x; const float* h; const float* c;
    const float* Wx[4]; const float* Wh[4]; const float* bx[4];
    float* oh; float* oc;
};

__global__ __launch_bounds__(256, 2) void relulstm_fallback(Params p) {
    __shared__ short sA[128 * 64];
    __shared__ short sB[4][64 * 64];
    const int t = threadIdx.x;
    const int bm = blockIdx.x * 128;
    const int bn = blockIdx.y * 64;
    const int wave = t >> 6;
    const int lane = t & 63;
    const int wm = (wave >> 1) * 64;
    const int wn = (wave & 1) * 32;
    const int lr = lane & 15;
    const int lk = (lane >> 4) * 8;

    f32x4 acc[4][4][2];
    #pragma unroll
    for (int g = 0; g < 4; ++g)
        #pragma unroll
        for (int m = 0; m < 4; ++m)
            #pragma unroll
            for (int n = 0; n < 2; ++n)
                acc[g][m][n] = (f32x4){0.f, 0.f, 0.f, 0.f};

    for (int k0 = 0; k0 < 2 * HID; k0 += BK) {
        const bool xpart = (k0 < HID);
        const int kb = k0 & (HID - 1);
        const float* __restrict__ srcA = xpart ? p.x : p.h;
        #pragma unroll
        for (int i2 = 0; i2 < 8; ++i2) {
            int cidx = t + i2 * 256;
            int row = cidx >> 4;
            int kc = cidx & 15;
            float4 v = *(const float4*)&srcA[(size_t)(bm + row) * HID + kb + kc * 4];
            int idx = row * BK + ((kc * 4) ^ ((row & 7) << 3));
            short4 s;
            s.x = f2bf(v.x); s.y = f2bf(v.y); s.z = f2bf(v.z); s.w = f2bf(v.w);
            *(short4*)&sA[idx] = s;
        }
        #pragma unroll
        for (int i2 = 0; i2 < 16; ++i2) {
            const int g = i2 >> 2;
            int rem = t + (i2 & 3) * 256;
            int row = rem >> 4;
            int kc = rem & 15;
            const float* __restrict__ srcB = xpart ? p.Wx[g] : p.Wh[g];
            float4 v = *(const float4*)&srcB[(size_t)(bn + row) * HID + kb + kc * 4];
            int idx = row * BK + ((kc * 4) ^ ((row & 7) << 3));
            short4 s;
            s.x = f2bf(v.x); s.y = f2bf(v.y); s.z = f2bf(v.z); s.w = f2bf(v.w);
            *(short4*)&sB[g][idx] = s;
        }
        __syncthreads();
        #pragma unroll
        for (int kk = 0; kk < 2; ++kk) {
            bf16x8 a[4];
            #pragma unroll
            for (int m = 0; m < 4; ++m) {
                int row = wm + m * 16 + lr;
                int kidx = (kk * 32 + lk) ^ ((row & 7) << 3);
                a[m] = *(const bf16x8*)&sA[row * BK + kidx];
            }
            #pragma unroll
            for (int g = 0; g < 4; ++g) {
                #pragma unroll
                for (int n = 0; n < 2; ++n) {
                    int brow = wn + n * 16 + lr;
                    int kidx = (kk * 32 + lk) ^ ((brow & 7) << 3);
                    bf16x8 b = *(const bf16x8*)&sB[g][brow * BK + kidx];
                    #pragma unroll
                    for (int m = 0; m < 4; ++m)
                        acc[g][m][n] = __builtin_amdgcn_mfma_f32_16x16x32_bf16(
                            a[m], b, acc[g][m][n], 0, 0, 0);
                }
            }
        }
        __syncthreads();
    }

    float bias[4][2];
    #pragma unroll
    for (int g = 0; g < 4; ++g)
        #pragma unroll
        for (int n = 0; n < 2; ++n)
            bias[g][n] = p.bx[g][bn + wn + n * 16 + lr];

    #pragma unroll
    for (int m = 0; m < 4; ++m) {
        int rbase = bm + wm + m * 16 + (lane >> 4) * 4;
        #pragma unroll
        for (int r = 0; r < 4; ++r) {
            int row = rbase + r;
            #pragma unroll
            for (int n = 0; n < 2; ++n) {
                int col = bn + wn + n * 16 + lr;
                float pf = acc[0][m][n][r] + bias[0][n];
                float pi = acc[1][m][n][r] + bias[1][n];
                float pc = acc[2][m][n][r] + bias[2][n];
                float po = acc[3][m][n][r] + bias[3][n];
                float fg = fmaxf(pf, 0.f);
                float ig = fmaxf(pi, 0.f);
                float og = fmaxf(po, 0.f);
                float ct = fast_tanh(pc);
                float cv = p.c[(size_t)row * HID + col];
                float cn = fg * cv + ig * ct;
                float hn = og * fast_tanh(cn);
                p.oh[(size_t)row * HID + col] = hn;
                p.oc[(size_t)row * HID + col] = cn;
            }
        }
    }
}

extern "C" void kernel_launch(void* const* d_in, const int* in_sizes, int n_in,
                              void* d_out, int out_size, void* d_ws, size_t ws_size,
                              hipStream_t stream) {
    (void)in_sizes; (void)n_in; (void)out_size;
    const size_t A_BYTES = (size_t)BATCH_N * KTOT * 2;
    const size_t B_BYTES = (size_t)4 * HID * KTOT * 2;

    if (ws_size >= A_BYTES + B_BYTES) {
        short* A = (short*)d_ws;
        short* B = A + (size_t)BATCH_N * KTOT;

        CastParams q;
        q.x = (const float*)d_in[0];
        q.h = (const float*)d_in[1];
        for (int g = 0; g < 4; ++g) {
            q.Wx[g] = (const float*)d_in[3 + 3 * g];
            q.Wh[g] = (const float*)d_in[5 + 3 * g];
        }
        q.A = A; q.B = B;
        precast_kernel<<<2048, 256, 0, stream>>>(q);

        GemmParams p;
        p.A = A; p.B = B;
        p.c = (const float*)d_in[2];
        for (int g = 0; g < 4; ++g) p.bx[g] = (const float*)d_in[4 + 3 * g];
        p.oh = (float*)d_out;
        p.oc = (float*)d_out + (size_t)BATCH_N * HID;
        dim3 grid(BATCH_N / 256, HID / 64);   // 16 x 32
        gemm_lstm_pipe<<<grid, 512, 0, stream>>>(p);
    } else {
        Params p;
        p.x = (const float*)d_in[0];
        p.h = (const float*)d_in[1];
        p.c = (const float*)d_in[2];
        for (int g = 0; g < 4; ++g) {
            p.Wx[g] = (const float*)d_in[3 + 3 * g];
            p.bx[g] = (const float*)d_in[4 + 3 * g];
            p.Wh[g] = (const float*)d_in[5 + 3 * g];
        }
        p.oh = (float*)d_out;
        p.oc = (float*)d_out + (size_t)BATCH_N * HID;
        dim3 grid(BATCH_N / 128, HID / 64);
        relulstm_fallback<<<grid, 256, 0, stream>>>(p);
    }
}